// Round 1
// baseline (739.014 us; speedup 1.0000x reference)
//
#include <hip/hip_runtime.h>

#define WS_ALIGN(x) (((x) + size_t(255)) & ~size_t(255))

// ---------------- CSR build ----------------

__global__ void count_kernel(const int* __restrict__ dst, int E, int* __restrict__ deg) {
    int i = blockIdx.x * blockDim.x + threadIdx.x;
    if (i < E) atomicAdd(&deg[dst[i]], 1);
}

__global__ __launch_bounds__(1024) void scan_part(const int* __restrict__ deg,
                                                  int* __restrict__ roff,
                                                  int* __restrict__ partials,
                                                  float* __restrict__ dinv, int N) {
    __shared__ int lds[1024];
    int tid = threadIdx.x;
    int g = blockIdx.x * 1024 + tid;
    int v = (g < N) ? deg[g] : 0;
    if (g < N) dinv[g] = rsqrtf((float)(v + 1));  // +1 self-loop
    lds[tid] = v;
    __syncthreads();
    for (int off = 1; off < 1024; off <<= 1) {
        int t = (tid >= off) ? lds[tid - off] : 0;
        __syncthreads();
        if (tid >= off) lds[tid] += t;
        __syncthreads();
    }
    if (g < N) roff[g] = lds[tid] - v;  // exclusive
    if (tid == 1023) partials[blockIdx.x] = lds[1023];
}

__global__ void scan_tot(int* __restrict__ partials, int n) {
    __shared__ int lds[128];
    int tid = threadIdx.x;
    int v = (tid < n) ? partials[tid] : 0;
    lds[tid] = v;
    __syncthreads();
    for (int off = 1; off < 128; off <<= 1) {
        int t = (tid >= off) ? lds[tid - off] : 0;
        __syncthreads();
        if (tid >= off) lds[tid] += t;
        __syncthreads();
    }
    if (tid < n) partials[tid] = lds[tid] - v;  // exclusive over chunks
}

__global__ void scan_add(int* __restrict__ roff, const int* __restrict__ partials,
                         int N, int Etot) {
    int i = blockIdx.x * blockDim.x + threadIdx.x;
    if (i < N) roff[i] += partials[i >> 10];
    if (i == 0) roff[N] = Etot;
}

__global__ void scatter_kernel(const int* __restrict__ src, const int* __restrict__ dst,
                               int E, const int* __restrict__ roff, int* __restrict__ cursor,
                               const float* __restrict__ dinv, int2* __restrict__ edges) {
    int i = blockIdx.x * blockDim.x + threadIdx.x;
    if (i >= E) return;
    int s = src[i], d = dst[i];
    int pos = roff[d] + atomicAdd(&cursor[d], 1);
    edges[pos] = make_int2(s, __float_as_int(dinv[s] * dinv[d]));
}

// ---------------- GEMM (K=128 fixed), optional fused BN+ReLU on A ----------------
// Tile: 64 rows x TN cols, 256 threads, each thread 4 rows x (TN/16) cols.

template <int TN, bool BN>
__global__ __launch_bounds__(256) void gemm_k128(const float* __restrict__ A,
                                                 const float* __restrict__ W,
                                                 const float* __restrict__ scale,
                                                 const float* __restrict__ shift,
                                                 float* __restrict__ C, int M) {
    constexpr int TM = 64, KC = 32;
    constexpr int CPT = TN / 16;  // 8 (TN=128) or 4 (TN=64)
    __shared__ float As[KC][TM];   // transposed A tile
    __shared__ float Ws[KC][TN];
    int tid = threadIdx.x;
    int tcol = tid & 15, trow = tid >> 4;
    int r0 = trow * 4, c0 = tcol * CPT;
    int rowBase = blockIdx.x * TM;

    float acc[4][CPT];
#pragma unroll
    for (int i = 0; i < 4; ++i)
#pragma unroll
        for (int j = 0; j < CPT; ++j) acc[i][j] = 0.f;

    for (int kc = 0; kc < 128; kc += KC) {
        // A tile: 64 rows x 32 k = 512 float4, 2 per thread
#pragma unroll
        for (int l = tid; l < TM * KC / 4; l += 256) {
            int r = l >> 3;
            int kf = (l & 7) << 2;
            int grow = rowBase + r;
            float4 v = make_float4(0.f, 0.f, 0.f, 0.f);
            if (grow < M) v = *(const float4*)&A[(size_t)grow * 128 + kc + kf];
            if (BN) {
                int k = kc + kf;
                v.x = fmaxf(fmaf(v.x, scale[k + 0], shift[k + 0]), 0.f);
                v.y = fmaxf(fmaf(v.y, scale[k + 1], shift[k + 1]), 0.f);
                v.z = fmaxf(fmaf(v.z, scale[k + 2], shift[k + 2]), 0.f);
                v.w = fmaxf(fmaf(v.w, scale[k + 3], shift[k + 3]), 0.f);
            }
            As[kf + 0][r] = v.x;
            As[kf + 1][r] = v.y;
            As[kf + 2][r] = v.z;
            As[kf + 3][r] = v.w;
        }
        // W tile: KC x TN floats
#pragma unroll
        for (int l = tid; l < KC * TN / 4; l += 256) {
            int k = l / (TN / 4);
            int cf = (l % (TN / 4)) * 4;
            *(float4*)&Ws[k][cf] = *(const float4*)&W[(size_t)(kc + k) * TN + cf];
        }
        __syncthreads();
#pragma unroll
        for (int kk = 0; kk < KC; ++kk) {
            float4 a4 = *(const float4*)&As[kk][r0];
            float av[4] = {a4.x, a4.y, a4.z, a4.w};
            float bv[CPT];
#pragma unroll
            for (int j = 0; j < CPT; j += 4) {
                float4 b4 = *(const float4*)&Ws[kk][c0 + j];
                bv[j] = b4.x; bv[j + 1] = b4.y; bv[j + 2] = b4.z; bv[j + 3] = b4.w;
            }
#pragma unroll
            for (int i = 0; i < 4; ++i)
#pragma unroll
                for (int j = 0; j < CPT; ++j) acc[i][j] = fmaf(av[i], bv[j], acc[i][j]);
        }
        __syncthreads();
    }
#pragma unroll
    for (int i = 0; i < 4; ++i) {
        int gr = rowBase + r0 + i;
        if (gr < M) {
#pragma unroll
            for (int j = 0; j < CPT; j += 4) {
                float4 o = make_float4(acc[i][j], acc[i][j + 1], acc[i][j + 2], acc[i][j + 3]);
                *(float4*)&C[(size_t)gr * TN + c0 + j] = o;
            }
        }
    }
}

// ---------------- SpMM (CSR gather), one wave per node ----------------

__global__ __launch_bounds__(256) void spmm128(const float* __restrict__ h,
                                               const int* __restrict__ roff,
                                               const int2* __restrict__ edges,
                                               const float* __restrict__ dinv,
                                               float* __restrict__ out, int N) {
    int node = blockIdx.x * 4 + (threadIdx.x >> 6);
    if (node >= N) return;
    int lane = threadIdx.x & 63;
    const float2* hp = (const float2*)h;
    float di = dinv[node];
    float sw = di * di;
    float2 v = hp[(size_t)node * 64 + lane];
    float ax = sw * v.x, ay = sw * v.y;
    int e0 = roff[node], e1 = roff[node + 1];
    for (int e = e0; e < e1; ++e) {
        int2 ed = edges[e];
        float w = __int_as_float(ed.y);
        float2 u = hp[(size_t)ed.x * 64 + lane];
        ax = fmaf(w, u.x, ax);
        ay = fmaf(w, u.y, ay);
    }
    ((float2*)out)[(size_t)node * 64 + lane] = make_float2(ax, ay);
}

__global__ __launch_bounds__(256) void spmm64(const float* __restrict__ h,
                                              const int* __restrict__ roff,
                                              const int2* __restrict__ edges,
                                              const float* __restrict__ dinv,
                                              float* __restrict__ out, int N) {
    int node = blockIdx.x * 4 + (threadIdx.x >> 6);
    if (node >= N) return;
    int lane = threadIdx.x & 63;
    float di = dinv[node];
    float acc = di * di * h[(size_t)node * 64 + lane];
    int e0 = roff[node], e1 = roff[node + 1];
    for (int e = e0; e < e1; ++e) {
        int2 ed = edges[e];
        float w = __int_as_float(ed.y);
        acc = fmaf(w, h[(size_t)ed.x * 64 + lane], acc);
    }
    out[(size_t)node * 64 + lane] = acc;
}

// ---------------- BatchNorm stats / apply ----------------

__global__ __launch_bounds__(256) void col_reduce(const float* __restrict__ a, int M, int F,
                                                  float* __restrict__ sums) {
    int c = threadIdx.x % F;
    int rpi = 256 / F;
    int rsub = threadIdx.x / F;
    float s = 0.f, q = 0.f;
    for (int r = blockIdx.x * rpi + rsub; r < M; r += gridDim.x * rpi) {
        float v = a[(size_t)r * F + c];
        s += v;
        q += v * v;
    }
    __shared__ float ls[256], lq[256];
    ls[threadIdx.x] = s;
    lq[threadIdx.x] = q;
    __syncthreads();
    if (threadIdx.x < F) {
        for (int t = threadIdx.x + F; t < 256; t += F) {
            s += ls[t];
            q += lq[t];
        }
        atomicAdd(&sums[c], s);
        atomicAdd(&sums[F + c], q);
    }
}

__global__ void bn_final(const float* __restrict__ sums, const float* __restrict__ gamma,
                         const float* __restrict__ beta, int M, int F,
                         float* __restrict__ scale, float* __restrict__ shift) {
    int c = threadIdx.x;
    if (c >= F) return;
    float mean = sums[c] / (float)M;
    float var = sums[F + c] / (float)M - mean * mean;
    float iv = rsqrtf(var + 1e-5f);
    float sc = gamma[c] * iv;
    scale[c] = sc;
    shift[c] = beta[c] - mean * sc;
}

__global__ void apply_bn64(const float* __restrict__ a, const float* __restrict__ scale,
                           const float* __restrict__ shift, float* __restrict__ out, int n4) {
    int i = blockIdx.x * blockDim.x + threadIdx.x;
    if (i >= n4) return;
    float4 v = ((const float4*)a)[i];
    int c0 = (i & 15) * 4;  // F=64 -> 16 float4 per row
    float4 sc = *(const float4*)&scale[c0];
    float4 sh = *(const float4*)&shift[c0];
    v.x = fmaf(v.x, sc.x, sh.x);
    v.y = fmaf(v.y, sc.y, sh.y);
    v.z = fmaf(v.z, sc.z, sh.z);
    v.w = fmaf(v.w, sc.w, sh.w);
    ((float4*)out)[i] = v;
}

// ---------------- launch ----------------

extern "C" void kernel_launch(void* const* d_in, const int* in_sizes, int n_in,
                              void* d_out, int out_size, void* d_ws, size_t ws_size,
                              hipStream_t stream) {
    const float* x      = (const float*)d_in[0];
    const float* W1     = (const float*)d_in[1];
    const float* gamma1 = (const float*)d_in[3];
    const float* beta1  = (const float*)d_in[4];
    const float* W2     = (const float*)d_in[5];
    const float* gamma2 = (const float*)d_in[7];
    const float* beta2  = (const float*)d_in[8];
    const int*   ei     = (const int*)d_in[9];

    const int hid  = in_sizes[2];            // 128
    const int outc = in_sizes[6];            // 64
    const int inc  = in_sizes[1] / hid;      // 128
    const int N    = in_sizes[0] / inc;      // 100000
    const int E    = in_sizes[9] / 2;        // 1600000
    const int* srcp = ei;
    const int* dstp = ei + E;

    char* wsp = (char*)d_ws;
    size_t off = 0;
    auto alloc = [&](size_t bytes) -> void* {
        void* p = wsp + off;
        off += WS_ALIGN(bytes);
        return p;
    };
    // zeroed region first
    int*   deg    = (int*)alloc((size_t)N * 4);
    int*   cursor = (int*)alloc((size_t)N * 4);
    float* sums1  = (float*)alloc((size_t)2 * hid * 4);
    float* sums2  = (float*)alloc((size_t)2 * outc * 4);
    size_t zeroBytes = off;
    // rest
    int*   roff     = (int*)alloc((size_t)(N + 1) * 4);
    float* dinv     = (float*)alloc((size_t)N * 4);
    int    nchunks  = (N + 1023) / 1024;
    int*   partials = (int*)alloc((size_t)nchunks * 4);
    float* scale1   = (float*)alloc((size_t)hid * 4);
    float* shift1   = (float*)alloc((size_t)hid * 4);
    float* scale2   = (float*)alloc((size_t)outc * 4);
    float* shift2   = (float*)alloc((size_t)outc * 4);
    int2*  edges    = (int2*)alloc((size_t)E * 8);
    float* h1       = (float*)alloc((size_t)N * hid * 4);
    float* agg1     = (float*)alloc((size_t)N * hid * 4);
    float* h2       = h1;                       // h1 dead after spmm128
    float* agg2     = h1 + (size_t)N * outc;    // disjoint from h2 within h1 region

    hipMemsetAsync(d_ws, 0, zeroBytes, stream);

    count_kernel<<<(E + 255) / 256, 256, 0, stream>>>(dstp, E, deg);
    scan_part<<<nchunks, 1024, 0, stream>>>(deg, roff, partials, dinv, N);
    scan_tot<<<1, 128, 0, stream>>>(partials, nchunks);
    scan_add<<<(N + 255) / 256, 256, 0, stream>>>(roff, partials, N, E);
    scatter_kernel<<<(E + 255) / 256, 256, 0, stream>>>(srcp, dstp, E, roff, cursor, dinv, edges);

    // layer 1: h1 = x @ W1 ; agg1 = Anorm @ h1 ; BN1 stats (bias cancels in BN)
    gemm_k128<128, false><<<(N + 63) / 64, 256, 0, stream>>>(x, W1, nullptr, nullptr, h1, N);
    spmm128<<<(N + 3) / 4, 256, 0, stream>>>(h1, roff, edges, dinv, agg1, N);
    col_reduce<<<256, 256, 0, stream>>>(agg1, N, 128, sums1);
    bn_final<<<1, 128, 0, stream>>>(sums1, gamma1, beta1, N, 128, scale1, shift1);

    // layer 2: h2 = relu(BN1(agg1)) @ W2 ; agg2 = Anorm @ h2 ; BN2 -> out
    gemm_k128<64, true><<<(N + 63) / 64, 256, 0, stream>>>(agg1, W2, scale1, shift1, h2, N);
    spmm64<<<(N + 3) / 4, 256, 0, stream>>>(h2, roff, edges, dinv, agg2, N);
    col_reduce<<<256, 256, 0, stream>>>(agg2, N, 64, sums2);
    bn_final<<<1, 64, 0, stream>>>(sums2, gamma2, beta2, N, 64, scale2, shift2);
    apply_bn64<<<(N * 64 / 4 + 255) / 256, 256, 0, stream>>>(agg2, scale2, shift2,
                                                             (float*)d_out, N * 64 / 4);
}

// Round 2
// 612.984 us; speedup vs baseline: 1.2056x; 1.2056x over previous
//
#include <hip/hip_runtime.h>

#define WS_ALIGN(x) (((x) + size_t(255)) & ~size_t(255))

// ---------------- CSR build ----------------

__global__ void count_kernel(const int* __restrict__ dst, int E, int* __restrict__ deg) {
    int i = blockIdx.x * blockDim.x + threadIdx.x;
    if (i < E) atomicAdd(&deg[dst[i]], 1);
}

__global__ __launch_bounds__(1024) void scan_part(const int* __restrict__ deg,
                                                  int* __restrict__ roff,
                                                  int* __restrict__ partials,
                                                  float* __restrict__ dinv, int N) {
    __shared__ int lds[1024];
    int tid = threadIdx.x;
    int g = blockIdx.x * 1024 + tid;
    int v = (g < N) ? deg[g] : 0;
    if (g < N) dinv[g] = rsqrtf((float)(v + 1));  // +1 self-loop
    lds[tid] = v;
    __syncthreads();
    for (int off = 1; off < 1024; off <<= 1) {
        int t = (tid >= off) ? lds[tid - off] : 0;
        __syncthreads();
        if (tid >= off) lds[tid] += t;
        __syncthreads();
    }
    if (g < N) roff[g] = lds[tid] - v;  // exclusive
    if (tid == 1023) partials[blockIdx.x] = lds[1023];
}

__global__ void scan_tot(int* __restrict__ partials, int n) {
    __shared__ int lds[128];
    int tid = threadIdx.x;
    int v = (tid < n) ? partials[tid] : 0;
    lds[tid] = v;
    __syncthreads();
    for (int off = 1; off < 128; off <<= 1) {
        int t = (tid >= off) ? lds[tid - off] : 0;
        __syncthreads();
        if (tid >= off) lds[tid] += t;
        __syncthreads();
    }
    if (tid < n) partials[tid] = lds[tid] - v;  // exclusive over chunks
}

__global__ void scan_add(int* __restrict__ roff, const int* __restrict__ partials,
                         int N, int Etot) {
    int i = blockIdx.x * blockDim.x + threadIdx.x;
    if (i < N) roff[i] += partials[i >> 10];
    if (i == 0) roff[N] = Etot;
}

__global__ void scatter_kernel(const int* __restrict__ src, const int* __restrict__ dst,
                               int E, const int* __restrict__ roff, int* __restrict__ cursor,
                               const float* __restrict__ dinv, int2* __restrict__ edges) {
    int i = blockIdx.x * blockDim.x + threadIdx.x;
    if (i >= E) return;
    int s = src[i], d = dst[i];
    int pos = roff[d] + atomicAdd(&cursor[d], 1);
    edges[pos] = make_int2(s, __float_as_int(dinv[s] * dinv[d]));
}

// ---------------- GEMM (K=128 fixed), optional fused BN+ReLU on A ----------------

template <int TN, bool BN>
__global__ __launch_bounds__(256) void gemm_k128(const float* __restrict__ A,
                                                 const float* __restrict__ W,
                                                 const float* __restrict__ scale,
                                                 const float* __restrict__ shift,
                                                 float* __restrict__ C, int M) {
    constexpr int TM = 64, KC = 32;
    constexpr int CPT = TN / 16;  // 8 (TN=128) or 4 (TN=64)
    __shared__ float As[KC][TM];   // transposed A tile
    __shared__ float Ws[KC][TN];
    int tid = threadIdx.x;
    int tcol = tid & 15, trow = tid >> 4;
    int r0 = trow * 4, c0 = tcol * CPT;
    int rowBase = blockIdx.x * TM;

    float acc[4][CPT];
#pragma unroll
    for (int i = 0; i < 4; ++i)
#pragma unroll
        for (int j = 0; j < CPT; ++j) acc[i][j] = 0.f;

    for (int kc = 0; kc < 128; kc += KC) {
#pragma unroll
        for (int l = tid; l < TM * KC / 4; l += 256) {
            int r = l >> 3;
            int kf = (l & 7) << 2;
            int grow = rowBase + r;
            float4 v = make_float4(0.f, 0.f, 0.f, 0.f);
            if (grow < M) v = *(const float4*)&A[(size_t)grow * 128 + kc + kf];
            if (BN) {
                int k = kc + kf;
                v.x = fmaxf(fmaf(v.x, scale[k + 0], shift[k + 0]), 0.f);
                v.y = fmaxf(fmaf(v.y, scale[k + 1], shift[k + 1]), 0.f);
                v.z = fmaxf(fmaf(v.z, scale[k + 2], shift[k + 2]), 0.f);
                v.w = fmaxf(fmaf(v.w, scale[k + 3], shift[k + 3]), 0.f);
            }
            As[kf + 0][r] = v.x;
            As[kf + 1][r] = v.y;
            As[kf + 2][r] = v.z;
            As[kf + 3][r] = v.w;
        }
#pragma unroll
        for (int l = tid; l < KC * TN / 4; l += 256) {
            int k = l / (TN / 4);
            int cf = (l % (TN / 4)) * 4;
            *(float4*)&Ws[k][cf] = *(const float4*)&W[(size_t)(kc + k) * TN + cf];
        }
        __syncthreads();
#pragma unroll
        for (int kk = 0; kk < KC; ++kk) {
            float4 a4 = *(const float4*)&As[kk][r0];
            float av[4] = {a4.x, a4.y, a4.z, a4.w};
            float bv[CPT];
#pragma unroll
            for (int j = 0; j < CPT; j += 4) {
                float4 b4 = *(const float4*)&Ws[kk][c0 + j];
                bv[j] = b4.x; bv[j + 1] = b4.y; bv[j + 2] = b4.z; bv[j + 3] = b4.w;
            }
#pragma unroll
            for (int i = 0; i < 4; ++i)
#pragma unroll
                for (int j = 0; j < CPT; ++j) acc[i][j] = fmaf(av[i], bv[j], acc[i][j]);
        }
        __syncthreads();
    }
#pragma unroll
    for (int i = 0; i < 4; ++i) {
        int gr = rowBase + r0 + i;
        if (gr < M) {
#pragma unroll
            for (int j = 0; j < CPT; j += 4) {
                float4 o = make_float4(acc[i][j], acc[i][j + 1], acc[i][j + 2], acc[i][j + 3]);
                *(float4*)&C[(size_t)gr * TN + c0 + j] = o;
            }
        }
    }
}

// ---------------- SpMM (CSR gather), one wave per node, 4 edges in flight ----

__global__ __launch_bounds__(256) void spmm128(const float* __restrict__ h,
                                               const int* __restrict__ roff,
                                               const int2* __restrict__ edges,
                                               const float* __restrict__ dinv,
                                               float* __restrict__ out, int N) {
    int node = blockIdx.x * 4 + (threadIdx.x >> 6);
    if (node >= N) return;
    int lane = threadIdx.x & 63;
    const float2* hp = (const float2*)h;
    float di = dinv[node];
    float sw = di * di;
    float2 v = hp[(size_t)node * 64 + lane];
    float ax = sw * v.x, ay = sw * v.y;
    float bx = 0.f, by = 0.f;
    int e0 = roff[node], e1 = roff[node + 1];
    int e = e0;
    for (; e + 4 <= e1; e += 4) {
        int2 ed0 = edges[e + 0];
        int2 ed1 = edges[e + 1];
        int2 ed2 = edges[e + 2];
        int2 ed3 = edges[e + 3];
        float2 u0 = hp[(size_t)ed0.x * 64 + lane];
        float2 u1 = hp[(size_t)ed1.x * 64 + lane];
        float2 u2 = hp[(size_t)ed2.x * 64 + lane];
        float2 u3 = hp[(size_t)ed3.x * 64 + lane];
        float w0 = __int_as_float(ed0.y), w1 = __int_as_float(ed1.y);
        float w2 = __int_as_float(ed2.y), w3 = __int_as_float(ed3.y);
        ax = fmaf(w0, u0.x, ax); ay = fmaf(w0, u0.y, ay);
        bx = fmaf(w1, u1.x, bx); by = fmaf(w1, u1.y, by);
        ax = fmaf(w2, u2.x, ax); ay = fmaf(w2, u2.y, ay);
        bx = fmaf(w3, u3.x, bx); by = fmaf(w3, u3.y, by);
    }
    for (; e < e1; ++e) {
        int2 ed = edges[e];
        float w = __int_as_float(ed.y);
        float2 u = hp[(size_t)ed.x * 64 + lane];
        ax = fmaf(w, u.x, ax);
        ay = fmaf(w, u.y, ay);
    }
    ((float2*)out)[(size_t)node * 64 + lane] = make_float2(ax + bx, ay + by);
}

__global__ __launch_bounds__(256) void spmm64(const float* __restrict__ h,
                                              const int* __restrict__ roff,
                                              const int2* __restrict__ edges,
                                              const float* __restrict__ dinv,
                                              float* __restrict__ out, int N) {
    int node = blockIdx.x * 4 + (threadIdx.x >> 6);
    if (node >= N) return;
    int lane = threadIdx.x & 63;
    float di = dinv[node];
    float acc = di * di * h[(size_t)node * 64 + lane];
    float acc2 = 0.f;
    int e0 = roff[node], e1 = roff[node + 1];
    int e = e0;
    for (; e + 4 <= e1; e += 4) {
        int2 ed0 = edges[e + 0];
        int2 ed1 = edges[e + 1];
        int2 ed2 = edges[e + 2];
        int2 ed3 = edges[e + 3];
        float u0 = h[(size_t)ed0.x * 64 + lane];
        float u1 = h[(size_t)ed1.x * 64 + lane];
        float u2 = h[(size_t)ed2.x * 64 + lane];
        float u3 = h[(size_t)ed3.x * 64 + lane];
        acc = fmaf(__int_as_float(ed0.y), u0, acc);
        acc2 = fmaf(__int_as_float(ed1.y), u1, acc2);
        acc = fmaf(__int_as_float(ed2.y), u2, acc);
        acc2 = fmaf(__int_as_float(ed3.y), u3, acc2);
    }
    for (; e < e1; ++e) {
        int2 ed = edges[e];
        acc = fmaf(__int_as_float(ed.y), h[(size_t)ed.x * 64 + lane], acc);
    }
    out[(size_t)node * 64 + lane] = acc + acc2;
}

// ---------------- BatchNorm stats / apply ----------------

__global__ __launch_bounds__(256) void col_reduce(const float* __restrict__ a, int M, int F,
                                                  float* __restrict__ sums) {
    int c = threadIdx.x % F;
    int rpi = 256 / F;
    int rsub = threadIdx.x / F;
    float s = 0.f, q = 0.f;
    for (int r = blockIdx.x * rpi + rsub; r < M; r += gridDim.x * rpi) {
        float v = a[(size_t)r * F + c];
        s += v;
        q += v * v;
    }
    __shared__ float ls[256], lq[256];
    ls[threadIdx.x] = s;
    lq[threadIdx.x] = q;
    __syncthreads();
    if (threadIdx.x < F) {
        for (int t = threadIdx.x + F; t < 256; t += F) {
            s += ls[t];
            q += lq[t];
        }
        atomicAdd(&sums[c], s);
        atomicAdd(&sums[F + c], q);
    }
}

__global__ void bn_final(const float* __restrict__ sums, const float* __restrict__ gamma,
                         const float* __restrict__ beta, int M, int F,
                         float* __restrict__ scale, float* __restrict__ shift) {
    int c = threadIdx.x;
    if (c >= F) return;
    float mean = sums[c] / (float)M;
    float var = sums[F + c] / (float)M - mean * mean;
    float iv = rsqrtf(var + 1e-5f);
    float sc = gamma[c] * iv;
    scale[c] = sc;
    shift[c] = beta[c] - mean * sc;
}

__global__ void apply_bn64(const float* __restrict__ a, const float* __restrict__ scale,
                           const float* __restrict__ shift, float* __restrict__ out, int n4) {
    int i = blockIdx.x * blockDim.x + threadIdx.x;
    if (i >= n4) return;
    float4 v = ((const float4*)a)[i];
    int c0 = (i & 15) * 4;  // F=64 -> 16 float4 per row
    float4 sc = *(const float4*)&scale[c0];
    float4 sh = *(const float4*)&shift[c0];
    v.x = fmaf(v.x, sc.x, sh.x);
    v.y = fmaf(v.y, sc.y, sh.y);
    v.z = fmaf(v.z, sc.z, sh.z);
    v.w = fmaf(v.w, sc.w, sh.w);
    ((float4*)out)[i] = v;
}

// ---------------- launch ----------------

extern "C" void kernel_launch(void* const* d_in, const int* in_sizes, int n_in,
                              void* d_out, int out_size, void* d_ws, size_t ws_size,
                              hipStream_t stream) {
    const float* x      = (const float*)d_in[0];
    const float* W1     = (const float*)d_in[1];
    const float* gamma1 = (const float*)d_in[3];
    const float* beta1  = (const float*)d_in[4];
    const float* W2     = (const float*)d_in[5];
    const float* gamma2 = (const float*)d_in[7];
    const float* beta2  = (const float*)d_in[8];
    const int*   ei     = (const int*)d_in[9];

    const int hid  = in_sizes[2];            // 128
    const int outc = in_sizes[6];            // 64
    const int inc  = in_sizes[1] / hid;      // 128
    const int N    = in_sizes[0] / inc;      // 100000
    const int E    = in_sizes[9] / 2;        // 1600000
    const int* srcp = ei;
    const int* dstp = ei + E;

    char* wsp = (char*)d_ws;
    size_t off = 0;
    auto alloc = [&](size_t bytes) -> void* {
        void* p = wsp + off;
        off += WS_ALIGN(bytes);
        return p;
    };
    // zeroed region first
    int*   deg    = (int*)alloc((size_t)N * 4);
    int*   cursor = (int*)alloc((size_t)N * 4);
    float* sums1  = (float*)alloc((size_t)2 * hid * 4);
    float* sums2  = (float*)alloc((size_t)2 * outc * 4);
    size_t zeroBytes = off;
    // rest
    int*   roff     = (int*)alloc((size_t)(N + 1) * 4);
    float* dinv     = (float*)alloc((size_t)N * 4);
    int    nchunks  = (N + 1023) / 1024;
    int*   partials = (int*)alloc((size_t)nchunks * 4);
    float* scale1   = (float*)alloc((size_t)hid * 4);
    float* shift1   = (float*)alloc((size_t)hid * 4);
    float* scale2   = (float*)alloc((size_t)outc * 4);
    float* shift2   = (float*)alloc((size_t)outc * 4);
    int2*  edges    = (int2*)alloc((size_t)E * 8);
    float* h1       = (float*)alloc((size_t)N * hid * 4);
    float* agg1     = (float*)alloc((size_t)N * hid * 4);
    float* h2       = h1;                       // h1 dead after spmm128
    float* agg2     = h1 + (size_t)N * outc;    // disjoint from h2 within h1 region

    hipMemsetAsync(d_ws, 0, zeroBytes, stream);

    count_kernel<<<(E + 255) / 256, 256, 0, stream>>>(dstp, E, deg);
    scan_part<<<nchunks, 1024, 0, stream>>>(deg, roff, partials, dinv, N);
    scan_tot<<<1, 128, 0, stream>>>(partials, nchunks);
    scan_add<<<(N + 255) / 256, 256, 0, stream>>>(roff, partials, N, E);
    scatter_kernel<<<(E + 255) / 256, 256, 0, stream>>>(srcp, dstp, E, roff, cursor, dinv, edges);

    // layer 1: h1 = x @ W1 ; agg1 = Anorm @ h1 ; BN1 stats (bias cancels in BN)
    gemm_k128<128, false><<<(N + 63) / 64, 256, 0, stream>>>(x, W1, nullptr, nullptr, h1, N);
    spmm128<<<(N + 3) / 4, 256, 0, stream>>>(h1, roff, edges, dinv, agg1, N);
    col_reduce<<<256, 256, 0, stream>>>(agg1, N, 128, sums1);
    bn_final<<<1, 128, 0, stream>>>(sums1, gamma1, beta1, N, 128, scale1, shift1);

    // layer 2: h2 = relu(BN1(agg1)) @ W2 ; agg2 = Anorm @ h2 ; BN2 -> out
    gemm_k128<64, true><<<(N + 63) / 64, 256, 0, stream>>>(agg1, W2, scale1, shift1, h2, N);
    spmm64<<<(N + 3) / 4, 256, 0, stream>>>(h2, roff, edges, dinv, agg2, N);
    col_reduce<<<256, 256, 0, stream>>>(agg2, N, 64, sums2);
    bn_final<<<1, 64, 0, stream>>>(sums2, gamma2, beta2, N, 64, scale2, shift2);
    apply_bn64<<<(N * 64 / 4 + 255) / 256, 256, 0, stream>>>(agg2, scale2, shift2,
                                                             (float*)d_out, N * 64 / 4);
}

// Round 3
// 571.100 us; speedup vs baseline: 1.2940x; 1.0733x over previous
//
#include <hip/hip_runtime.h>

#define WS_ALIGN(x) (((x) + size_t(255)) & ~size_t(255))

typedef unsigned int uint;
typedef unsigned short ushort;

__device__ __forceinline__ ushort f2bf(float f) {
    uint u = __float_as_uint(f);
    return (ushort)((u + 0x7fff + ((u >> 16) & 1)) >> 16);  // RNE
}
__device__ __forceinline__ float bflo(uint u) { return __uint_as_float(u << 16); }
__device__ __forceinline__ float bfhi(uint u) { return __uint_as_float(u & 0xffff0000u); }
__device__ __forceinline__ float bf1(ushort s) { return __uint_as_float(((uint)s) << 16); }

// ---------------- CSR build ----------------

__global__ void count_kernel(const int* __restrict__ dst, int E, int* __restrict__ deg) {
    int i = blockIdx.x * blockDim.x + threadIdx.x;
    if (i < E) atomicAdd(&deg[dst[i]], 1);
}

__global__ __launch_bounds__(1024) void scan_part(const int* __restrict__ deg,
                                                  int* __restrict__ roff,
                                                  int* __restrict__ partials,
                                                  float* __restrict__ dinv, int N) {
    __shared__ int lds[1024];
    int tid = threadIdx.x;
    int g = blockIdx.x * 1024 + tid;
    int v = (g < N) ? deg[g] : 0;
    if (g < N) dinv[g] = rsqrtf((float)(v + 1));  // +1 self-loop
    lds[tid] = v;
    __syncthreads();
    for (int off = 1; off < 1024; off <<= 1) {
        int t = (tid >= off) ? lds[tid - off] : 0;
        __syncthreads();
        if (tid >= off) lds[tid] += t;
        __syncthreads();
    }
    if (g < N) roff[g] = lds[tid] - v;  // exclusive
    if (tid == 1023) partials[blockIdx.x] = lds[1023];
}

__global__ void scan_tot(int* __restrict__ partials, int n) {
    __shared__ int lds[128];
    int tid = threadIdx.x;
    int v = (tid < n) ? partials[tid] : 0;
    lds[tid] = v;
    __syncthreads();
    for (int off = 1; off < 128; off <<= 1) {
        int t = (tid >= off) ? lds[tid - off] : 0;
        __syncthreads();
        if (tid >= off) lds[tid] += t;
        __syncthreads();
    }
    if (tid < n) partials[tid] = lds[tid] - v;  // exclusive over chunks
}

__global__ void scan_add(int* __restrict__ roff, const int* __restrict__ partials,
                         int N, int Etot) {
    int i = blockIdx.x * blockDim.x + threadIdx.x;
    if (i < N) roff[i] += partials[i >> 10];
    if (i == 0) roff[N] = Etot;
}

__global__ void scatter_kernel(const int* __restrict__ src, const int* __restrict__ dst,
                               int E, const int* __restrict__ roff, int* __restrict__ cursor,
                               const float* __restrict__ dinv, int2* __restrict__ edges) {
    int i = blockIdx.x * blockDim.x + threadIdx.x;
    if (i >= E) return;
    int s = src[i], d = dst[i];
    int pos = roff[d] + atomicAdd(&cursor[d], 1);
    edges[pos] = make_int2(s, __float_as_int(dinv[s] * dinv[d]));
}

// ---------------- GEMM (K=128 fixed), optional fused BN+ReLU on A, bf16 out ----

template <int TN, bool BN>
__global__ __launch_bounds__(256) void gemm_k128(const float* __restrict__ A,
                                                 const float* __restrict__ W,
                                                 const float* __restrict__ scale,
                                                 const float* __restrict__ shift,
                                                 ushort* __restrict__ Cb, int M) {
    constexpr int TM = 64, KC = 32;
    constexpr int CPT = TN / 16;  // 8 (TN=128) or 4 (TN=64)
    __shared__ float As[KC][TM];   // transposed A tile
    __shared__ float Ws[KC][TN];
    int tid = threadIdx.x;
    int tcol = tid & 15, trow = tid >> 4;
    int r0 = trow * 4, c0 = tcol * CPT;
    int rowBase = blockIdx.x * TM;

    float acc[4][CPT];
#pragma unroll
    for (int i = 0; i < 4; ++i)
#pragma unroll
        for (int j = 0; j < CPT; ++j) acc[i][j] = 0.f;

    for (int kc = 0; kc < 128; kc += KC) {
#pragma unroll
        for (int l = tid; l < TM * KC / 4; l += 256) {
            int r = l >> 3;
            int kf = (l & 7) << 2;
            int grow = rowBase + r;
            float4 v = make_float4(0.f, 0.f, 0.f, 0.f);
            if (grow < M) v = *(const float4*)&A[(size_t)grow * 128 + kc + kf];
            if (BN) {
                int k = kc + kf;
                v.x = fmaxf(fmaf(v.x, scale[k + 0], shift[k + 0]), 0.f);
                v.y = fmaxf(fmaf(v.y, scale[k + 1], shift[k + 1]), 0.f);
                v.z = fmaxf(fmaf(v.z, scale[k + 2], shift[k + 2]), 0.f);
                v.w = fmaxf(fmaf(v.w, scale[k + 3], shift[k + 3]), 0.f);
            }
            As[kf + 0][r] = v.x;
            As[kf + 1][r] = v.y;
            As[kf + 2][r] = v.z;
            As[kf + 3][r] = v.w;
        }
#pragma unroll
        for (int l = tid; l < KC * TN / 4; l += 256) {
            int k = l / (TN / 4);
            int cf = (l % (TN / 4)) * 4;
            *(float4*)&Ws[k][cf] = *(const float4*)&W[(size_t)(kc + k) * TN + cf];
        }
        __syncthreads();
#pragma unroll
        for (int kk = 0; kk < KC; ++kk) {
            float4 a4 = *(const float4*)&As[kk][r0];
            float av[4] = {a4.x, a4.y, a4.z, a4.w};
            float bv[CPT];
#pragma unroll
            for (int j = 0; j < CPT; j += 4) {
                float4 b4 = *(const float4*)&Ws[kk][c0 + j];
                bv[j] = b4.x; bv[j + 1] = b4.y; bv[j + 2] = b4.z; bv[j + 3] = b4.w;
            }
#pragma unroll
            for (int i = 0; i < 4; ++i)
#pragma unroll
                for (int j = 0; j < CPT; ++j) acc[i][j] = fmaf(av[i], bv[j], acc[i][j]);
        }
        __syncthreads();
    }
#pragma unroll
    for (int i = 0; i < 4; ++i) {
        int gr = rowBase + r0 + i;
        if (gr < M) {
            uint p[CPT / 2];
#pragma unroll
            for (int j = 0; j < CPT; j += 2)
                p[j / 2] = (uint)f2bf(acc[i][j]) | ((uint)f2bf(acc[i][j + 1]) << 16);
            uint* dst = (uint*)&Cb[(size_t)gr * TN + c0];
#pragma unroll
            for (int j = 0; j < CPT / 2; ++j) dst[j] = p[j];
        }
    }
}

// ---------------- SpMM (CSR gather), bf16 rows, 8 edges in flight ----------

__global__ __launch_bounds__(256) void spmm128(const ushort* __restrict__ hb,
                                               const int* __restrict__ roff,
                                               const int2* __restrict__ edges,
                                               const float* __restrict__ dinv,
                                               float* __restrict__ out, int N) {
    int node = blockIdx.x * 4 + (threadIdx.x >> 6);
    if (node >= N) return;
    int lane = threadIdx.x & 63;
    const uint* hp = (const uint*)hb;  // 2 bf16 per uint, row = 64 uints
    float di = dinv[node];
    float sw = di * di;
    uint sv = hp[(size_t)node * 64 + lane];
    float ax = sw * bflo(sv), ay = sw * bfhi(sv);
    float bx = 0.f, by = 0.f;
    int e0 = roff[node], e1 = roff[node + 1];
    int e = e0;
    for (; e + 8 <= e1; e += 8) {
        int2 ed[8];
        uint u[8];
#pragma unroll
        for (int j = 0; j < 8; ++j) ed[j] = edges[e + j];
#pragma unroll
        for (int j = 0; j < 8; ++j) u[j] = hp[(size_t)ed[j].x * 64 + lane];
#pragma unroll
        for (int j = 0; j < 8; ++j) {
            float w = __int_as_float(ed[j].y);
            if (j & 1) {
                bx = fmaf(w, bflo(u[j]), bx);
                by = fmaf(w, bfhi(u[j]), by);
            } else {
                ax = fmaf(w, bflo(u[j]), ax);
                ay = fmaf(w, bfhi(u[j]), ay);
            }
        }
    }
    for (; e < e1; ++e) {
        int2 ed = edges[e];
        float w = __int_as_float(ed.y);
        uint u = hp[(size_t)ed.x * 64 + lane];
        ax = fmaf(w, bflo(u), ax);
        ay = fmaf(w, bfhi(u), ay);
    }
    ((float2*)out)[(size_t)node * 64 + lane] = make_float2(ax + bx, ay + by);
}

__global__ __launch_bounds__(256) void spmm64(const ushort* __restrict__ hb,
                                              const int* __restrict__ roff,
                                              const int2* __restrict__ edges,
                                              const float* __restrict__ dinv,
                                              float* __restrict__ out, int N) {
    int node = blockIdx.x * 4 + (threadIdx.x >> 6);
    if (node >= N) return;
    int lane = threadIdx.x & 63;
    float di = dinv[node];
    float acc = di * di * bf1(hb[(size_t)node * 64 + lane]);
    float acc2 = 0.f;
    int e0 = roff[node], e1 = roff[node + 1];
    int e = e0;
    for (; e + 8 <= e1; e += 8) {
        int2 ed[8];
        ushort u[8];
#pragma unroll
        for (int j = 0; j < 8; ++j) ed[j] = edges[e + j];
#pragma unroll
        for (int j = 0; j < 8; ++j) u[j] = hb[(size_t)ed[j].x * 64 + lane];
#pragma unroll
        for (int j = 0; j < 8; ++j) {
            float w = __int_as_float(ed[j].y);
            if (j & 1) acc2 = fmaf(w, bf1(u[j]), acc2);
            else       acc  = fmaf(w, bf1(u[j]), acc);
        }
    }
    for (; e < e1; ++e) {
        int2 ed = edges[e];
        acc = fmaf(__int_as_float(ed.y), bf1(hb[(size_t)ed.x * 64 + lane]), acc);
    }
    out[(size_t)node * 64 + lane] = acc + acc2;
}

// ---------------- BatchNorm stats / apply ----------------

__global__ __launch_bounds__(256) void col_reduce(const float* __restrict__ a, int M, int F,
                                                  float* __restrict__ sums) {
    int c = threadIdx.x % F;
    int rpi = 256 / F;
    int rsub = threadIdx.x / F;
    float s = 0.f, q = 0.f;
    for (int r = blockIdx.x * rpi + rsub; r < M; r += gridDim.x * rpi) {
        float v = a[(size_t)r * F + c];
        s += v;
        q += v * v;
    }
    __shared__ float ls[256], lq[256];
    ls[threadIdx.x] = s;
    lq[threadIdx.x] = q;
    __syncthreads();
    if (threadIdx.x < F) {
        for (int t = threadIdx.x + F; t < 256; t += F) {
            s += ls[t];
            q += lq[t];
        }
        atomicAdd(&sums[c], s);
        atomicAdd(&sums[F + c], q);
    }
}

__global__ void bn_final(const float* __restrict__ sums, const float* __restrict__ gamma,
                         const float* __restrict__ beta, int M, int F,
                         float* __restrict__ scale, float* __restrict__ shift) {
    int c = threadIdx.x;
    if (c >= F) return;
    float mean = sums[c] / (float)M;
    float var = sums[F + c] / (float)M - mean * mean;
    float iv = rsqrtf(var + 1e-5f);
    float sc = gamma[c] * iv;
    scale[c] = sc;
    shift[c] = beta[c] - mean * sc;
}

__global__ void apply_bn64(const float* __restrict__ a, const float* __restrict__ scale,
                           const float* __restrict__ shift, float* __restrict__ out, int n4) {
    int i = blockIdx.x * blockDim.x + threadIdx.x;
    if (i >= n4) return;
    float4 v = ((const float4*)a)[i];
    int c0 = (i & 15) * 4;  // F=64 -> 16 float4 per row
    float4 sc = *(const float4*)&scale[c0];
    float4 sh = *(const float4*)&shift[c0];
    v.x = fmaf(v.x, sc.x, sh.x);
    v.y = fmaf(v.y, sc.y, sh.y);
    v.z = fmaf(v.z, sc.z, sh.z);
    v.w = fmaf(v.w, sc.w, sh.w);
    ((float4*)out)[i] = v;
}

// ---------------- launch ----------------

extern "C" void kernel_launch(void* const* d_in, const int* in_sizes, int n_in,
                              void* d_out, int out_size, void* d_ws, size_t ws_size,
                              hipStream_t stream) {
    const float* x      = (const float*)d_in[0];
    const float* W1     = (const float*)d_in[1];
    const float* gamma1 = (const float*)d_in[3];
    const float* beta1  = (const float*)d_in[4];
    const float* W2     = (const float*)d_in[5];
    const float* gamma2 = (const float*)d_in[7];
    const float* beta2  = (const float*)d_in[8];
    const int*   ei     = (const int*)d_in[9];

    const int hid  = in_sizes[2];            // 128
    const int outc = in_sizes[6];            // 64
    const int inc  = in_sizes[1] / hid;      // 128
    const int N    = in_sizes[0] / inc;      // 100000
    const int E    = in_sizes[9] / 2;        // 1600000
    const int* srcp = ei;
    const int* dstp = ei + E;

    char* wsp = (char*)d_ws;
    size_t off = 0;
    auto alloc = [&](size_t bytes) -> void* {
        void* p = wsp + off;
        off += WS_ALIGN(bytes);
        return p;
    };
    // zeroed region first
    int*   deg    = (int*)alloc((size_t)N * 4);
    int*   cursor = (int*)alloc((size_t)N * 4);
    float* sums1  = (float*)alloc((size_t)2 * hid * 4);
    float* sums2  = (float*)alloc((size_t)2 * outc * 4);
    size_t zeroBytes = off;
    // rest
    int*   roff     = (int*)alloc((size_t)(N + 1) * 4);
    float* dinv     = (float*)alloc((size_t)N * 4);
    int    nchunks  = (N + 1023) / 1024;
    int*   partials = (int*)alloc((size_t)nchunks * 4);
    float* scale1   = (float*)alloc((size_t)hid * 4);
    float* shift1   = (float*)alloc((size_t)hid * 4);
    float* scale2   = (float*)alloc((size_t)outc * 4);
    float* shift2   = (float*)alloc((size_t)outc * 4);
    int2*  edges    = (int2*)alloc((size_t)E * 8);
    ushort* h1b     = (ushort*)alloc((size_t)N * hid * 2);   // bf16 h1
    float* agg1     = (float*)alloc((size_t)N * hid * 4);
    ushort* h2b     = h1b;          // h1b dead after spmm128
    float* agg2     = agg1;         // agg1 dead after gemm2 reads it

    hipMemsetAsync(d_ws, 0, zeroBytes, stream);

    count_kernel<<<(E + 255) / 256, 256, 0, stream>>>(dstp, E, deg);
    scan_part<<<nchunks, 1024, 0, stream>>>(deg, roff, partials, dinv, N);
    scan_tot<<<1, 128, 0, stream>>>(partials, nchunks);
    scan_add<<<(N + 255) / 256, 256, 0, stream>>>(roff, partials, N, E);
    scatter_kernel<<<(E + 255) / 256, 256, 0, stream>>>(srcp, dstp, E, roff, cursor, dinv, edges);

    // layer 1: h1 = x @ W1 (bf16 out) ; agg1 = Anorm @ h1 ; BN1 stats
    gemm_k128<128, false><<<(N + 63) / 64, 256, 0, stream>>>(x, W1, nullptr, nullptr, h1b, N);
    spmm128<<<(N + 3) / 4, 256, 0, stream>>>(h1b, roff, edges, dinv, agg1, N);
    col_reduce<<<256, 256, 0, stream>>>(agg1, N, 128, sums1);
    bn_final<<<1, 128, 0, stream>>>(sums1, gamma1, beta1, N, 128, scale1, shift1);

    // layer 2: h2 = relu(BN1(agg1)) @ W2 (bf16 out) ; agg2 = Anorm @ h2 ; BN2 -> out
    gemm_k128<64, true><<<(N + 63) / 64, 256, 0, stream>>>(agg1, W2, scale1, shift1, h2b, N);
    spmm64<<<(N + 3) / 4, 256, 0, stream>>>(h2b, roff, edges, dinv, agg2, N);
    col_reduce<<<256, 256, 0, stream>>>(agg2, N, 64, sums2);
    bn_final<<<1, 64, 0, stream>>>(sums2, gamma2, beta2, N, 64, scale2, shift2);
    apply_bn64<<<(N * 64 / 4 + 255) / 256, 256, 0, stream>>>(agg2, scale2, shift2,
                                                             (float*)d_out, N * 64 / 4);
}